// Round 4
// baseline (289.239 us; speedup 1.0000x reference)
//
#include <hip/hip_runtime.h>

// Problem constants: B=32, H=W=1024, N=96 boxes/batch.
#define BATCH 32
#define HDIM 1024
#define WDIM 1024
#define NBOX 96
#define THREADS 256
#define WAVES_PER_BLOCK 4
#define ROWS_PER_WAVE 4
#define NBLOCKS (BATCH * HDIM / (ROWS_PER_WAVE * WAVES_PER_BLOCK))   // 2048
// LDS layout: col c -> word 18*(c>>4) + (c&15). Words 18k+16, 18k+17 are gaps.
// Chunk base 18*lane words = 72*lane bytes -> 8B aligned -> ds_write_b64 x8.
// Banks: (18L+2j)%32 puts exactly 4 lanes on each bank pair -> optimal for
// the 4-phase b64 op (free). Gap word 16 = zero sentinel.
#define LDS_STRIDE 1152           // words per wave region (64*18)
#define ZERO_SLOT 16

__device__ __forceinline__ int padidx(int c) { return c + 2 * (c >> 4); }

// ---------------------------------------------------------------------------
// Kernel 0: zero per-box accumulators + ticket counter (ws poisoned 0xAA).
// ---------------------------------------------------------------------------
__global__ void init_kernel(float* __restrict__ ws) {
    const int t = threadIdx.x;
    for (int i = t; i < BATCH * NBOX; i += THREADS) ws[i] = 0.0f;
    if (t == 0) ((unsigned int*)ws)[BATCH * NBOX] = 0u;
}

// ---------------------------------------------------------------------------
// Kernel 1: wave-independent row prefix + box accumulation, fused finalize.
// Each wave owns ROWS_PER_WAVE rows of one batch image, private LDS region.
// Last-done block (device ticket) computes loss = sum relu(1 - box_sum).
// ---------------------------------------------------------------------------
__global__ __launch_bounds__(THREADS) void box_accum_kernel(
    const float* __restrict__ img,
    const int* __restrict__ bboxes,
    float* __restrict__ ws_box,
    float* __restrict__ out) {

    __shared__ float lds[WAVES_PER_BLOCK * LDS_STRIDE];   // 18432 B
    __shared__ unsigned int ticket_s;

    const int t = threadIdx.x;
    const int lane = t & 63;
    const int wave = t >> 6;
    float* __restrict__ P = lds + wave * LDS_STRIDE;

    const int gwave = blockIdx.x * WAVES_PER_BLOCK + wave;
    const int row0 = gwave * ROWS_PER_WAVE;          // global row; no batch crossing
    const int b = row0 / HDIM;
    const int hrow0 = row0 - b * HDIM;               // batch-local row

    if (lane == 0) P[ZERO_SLOT] = 0.0f;              // sentinel for x1==0 reads

    // --- box params: lane owns box `lane`; and box `lane+64` if lane<32 ---
    const int4* __restrict__ bb = (const int4*)bboxes + b * NBOX;
    int y1a = 0, y2a = 0, ra = ZERO_SLOT, la = ZERO_SLOT;
    int y1b = 0, y2b = 0, rb = ZERO_SLOT, lb = ZERO_SLOT;
    bool va = false, vb = false;
    {
        int4 q = bb[lane];
        int x1 = min(max(q.x, 0), WDIM), x2 = min(max(q.z, 0), WDIM);
        y1a = min(max(q.y, 0), WDIM);  y2a = min(max(q.w, 0), WDIM);
        va = (x2 > x1);
        if (va) { ra = padidx(x2 - 1); la = (x1 > 0) ? padidx(x1 - 1) : ZERO_SLOT; }
    }
    if (lane < NBOX - 64) {
        int4 q = bb[64 + lane];
        int x1 = min(max(q.x, 0), WDIM), x2 = min(max(q.z, 0), WDIM);
        y1b = min(max(q.y, 0), WDIM);  y2b = min(max(q.w, 0), WDIM);
        vb = (x2 > x1);
        if (vb) { rb = padidx(x2 - 1); lb = (x1 > 0) ? padidx(x1 - 1) : ZERO_SLOT; }
    }

    float acca = 0.0f, accb = 0.0f;
    const float* rowptr = img + (size_t)row0 * WDIM + lane * 16;

    // software-pipelined: prefetch row r+1 before processing row r
    const float4* lp = (const float4*)rowptr;
    float4 c0 = lp[0], c1 = lp[1], c2 = lp[2], c3 = lp[3];

    #pragma unroll
    for (int r = 0; r < ROWS_PER_WAVE; ++r) {
        float4 n0, n1, n2, n3;
        if (r + 1 < ROWS_PER_WAVE) {
            const float4* np = (const float4*)(rowptr + (size_t)(r + 1) * WDIM);
            n0 = np[0]; n1 = np[1]; n2 = np[2]; n3 = np[3];
        }

        float p[16];
        p[0]  = c0.x;         p[1]  = p[0]  + c0.y;
        p[2]  = p[1]  + c0.z; p[3]  = p[2]  + c0.w;
        p[4]  = p[3]  + c1.x; p[5]  = p[4]  + c1.y;
        p[6]  = p[5]  + c1.z; p[7]  = p[6]  + c1.w;
        p[8]  = p[7]  + c2.x; p[9]  = p[8]  + c2.y;
        p[10] = p[9]  + c2.z; p[11] = p[10] + c2.w;
        p[12] = p[11] + c3.x; p[13] = p[12] + c3.y;
        p[14] = p[13] + c3.z; p[15] = p[14] + c3.w;

        // one wave-inclusive scan of lane totals
        float T = p[15];
        float wscan = T;
        #pragma unroll
        for (int off = 1; off < 64; off <<= 1) {
            float u = __shfl_up(wscan, off, 64);
            if (lane >= off) wscan += u;
        }
        float E = wscan - T;   // exclusive base for this lane's chunk

        // 8x ds_write_b64, stride-18 layout (conflict-free)
        float2* Pw = (float2*)(P + 18 * lane);
        #pragma unroll
        for (int j = 0; j < 8; ++j)
            Pw[j] = make_float2(E + p[2 * j], E + p[2 * j + 1]);

        __builtin_amdgcn_wave_barrier();   // write->read order; DS pipe in-order per wave

        const int row = hrow0 + r;
        if (va && (y1a <= row) && (row < y2a)) acca += P[ra] - P[la];
        if (vb && (y1b <= row) && (row < y2b)) accb += P[rb] - P[lb];

        __builtin_amdgcn_wave_barrier();   // next row's writes after these reads

        c0 = n0; c1 = n1; c2 = n2; c3 = n3;
    }

    if (va && acca != 0.0f) atomicAdd(&ws_box[b * NBOX + lane], acca);
    if (vb && accb != 0.0f) atomicAdd(&ws_box[b * NBOX + 64 + lane], accb);

    // ---- last-done block performs the finalize ----
    __syncthreads();   // all this block's atomics complete (barrier drains vmcnt)
    if (t == 0) {
        __threadfence();
        ticket_s = atomicAdd((unsigned int*)(ws_box + BATCH * NBOX), 1u);
    }
    __syncthreads();
    if (ticket_s == NBLOCKS - 1) {
        __threadfence();   // acquire: see all blocks' atomic results
        float local = 0.0f;
        const int4* __restrict__ allbb = (const int4*)bboxes;
        for (int idx = t; idx < BATCH * NBOX; idx += THREADS) {
            const int4 q = allbb[idx];
            int x1 = min(max(q.x, 0), WDIM), y1 = min(max(q.y, 0), WDIM);
            int x2 = min(max(q.z, 0), WDIM), y2 = min(max(q.w, 0), WDIM);
            bool valid = (x2 > x1) && (y2 > y1);
            float s = valid ? __hip_atomic_load(&ws_box[idx], __ATOMIC_RELAXED,
                                                __HIP_MEMORY_SCOPE_AGENT)
                            : 0.0f;
            local += fmaxf(1.0f - s, 0.0f);
        }
        #pragma unroll
        for (int off = 32; off > 0; off >>= 1)
            local += __shfl_down(local, off, 64);
        if (lane == 0) lds[wave] = local;
        __syncthreads();
        if (t == 0) {
            float r = lds[0] + lds[1] + lds[2] + lds[3];
            out[0] = r;
        }
    }
}

// ---------------------------------------------------------------------------
extern "C" void kernel_launch(void* const* d_in, const int* in_sizes, int n_in,
                              void* d_out, int out_size, void* d_ws, size_t ws_size,
                              hipStream_t stream) {
    const float* img    = (const float*)d_in[0];   // (32,1,1024,1024) fp32
    const int*   bboxes = (const int*)d_in[1];     // (32,96,4) int32
    float* out = (float*)d_out;
    float* ws_box = (float*)d_ws;                  // 3072 floats + 1 uint ticket

    init_kernel<<<1, THREADS, 0, stream>>>(ws_box);
    box_accum_kernel<<<NBLOCKS, THREADS, 0, stream>>>(img, bboxes, ws_box, out);
}

// Round 5
// 199.838 us; speedup vs baseline: 1.4474x; 1.4474x over previous
//
#include <hip/hip_runtime.h>

// Problem constants: B=32, H=W=1024, N=96 boxes/batch.
#define BATCH 32
#define HDIM 1024
#define WDIM 1024
#define NBOX 96
#define THREADS 256
#define WAVES_PER_BLOCK 4
#define ROWS_PER_WAVE 4
#define NBLOCKS (BATCH * HDIM / (ROWS_PER_WAVE * WAVES_PER_BLOCK))   // 2048
// LDS layout: col c -> word 18*(c>>4) + (c&15). Words 18k+16, 18k+17 are gaps.
// Chunk base 18*lane words = 72*lane bytes -> 8B aligned -> ds_write_b64 x8.
// Banks: (18L+2j)%32 puts exactly 4 lanes on each bank pair -> optimal for
// the 4-phase b64 op. Gap word 16 = zero sentinel.
#define LDS_STRIDE 1152           // words per wave region (64*18)
#define ZERO_SLOT 16

__device__ __forceinline__ int padidx(int c) { return c + 2 * (c >> 4); }

// ---------------------------------------------------------------------------
// Kernel 0: zero the per-box accumulators (ws is poisoned 0xAA by harness).
// ---------------------------------------------------------------------------
__global__ void zero_ws_kernel(float* __restrict__ ws) {
    int i = blockIdx.x * blockDim.x + threadIdx.x;
    if (i < BATCH * NBOX) ws[i] = 0.0f;
}

// ---------------------------------------------------------------------------
// Kernel 1: wave-independent row prefix + box accumulation. NO block barriers,
// NO device fences (R4's fused-finalize threadfence/ticket cost ~90us of
// serialized L2 writebacks — reverted).
// Each wave owns ROWS_PER_WAVE rows of one batch image, private LDS region.
// box_sum(b,n) = sum over batch-local rows i in [y1,y2) of (P_i[x2]-P_i[x1]).
// ---------------------------------------------------------------------------
__global__ __launch_bounds__(THREADS) void box_accum_kernel(
    const float* __restrict__ img,
    const int* __restrict__ bboxes,
    float* __restrict__ ws_box) {

    __shared__ float lds[WAVES_PER_BLOCK * LDS_STRIDE];   // 18432 B

    const int t = threadIdx.x;
    const int lane = t & 63;
    const int wave = t >> 6;
    float* __restrict__ P = lds + wave * LDS_STRIDE;

    const int gwave = blockIdx.x * WAVES_PER_BLOCK + wave;
    const int row0 = gwave * ROWS_PER_WAVE;          // global row; no batch crossing
    const int b = row0 / HDIM;
    const int hrow0 = row0 - b * HDIM;               // batch-local row

    if (lane == 0) P[ZERO_SLOT] = 0.0f;              // sentinel for x1==0 reads

    // --- box params: lane owns box `lane`; and box `lane+64` if lane<32 ---
    const int4* __restrict__ bb = (const int4*)bboxes + b * NBOX;
    int y1a = 0, y2a = 0, ra = ZERO_SLOT, la = ZERO_SLOT;
    int y1b = 0, y2b = 0, rb = ZERO_SLOT, lb = ZERO_SLOT;
    bool va = false, vb = false;
    {
        int4 q = bb[lane];
        int x1 = min(max(q.x, 0), WDIM), x2 = min(max(q.z, 0), WDIM);
        y1a = min(max(q.y, 0), WDIM);  y2a = min(max(q.w, 0), WDIM);
        va = (x2 > x1);
        if (va) { ra = padidx(x2 - 1); la = (x1 > 0) ? padidx(x1 - 1) : ZERO_SLOT; }
    }
    if (lane < NBOX - 64) {
        int4 q = bb[64 + lane];
        int x1 = min(max(q.x, 0), WDIM), x2 = min(max(q.z, 0), WDIM);
        y1b = min(max(q.y, 0), WDIM);  y2b = min(max(q.w, 0), WDIM);
        vb = (x2 > x1);
        if (vb) { rb = padidx(x2 - 1); lb = (x1 > 0) ? padidx(x1 - 1) : ZERO_SLOT; }
    }

    float acca = 0.0f, accb = 0.0f;
    const float* rowptr = img + (size_t)row0 * WDIM + lane * 16;

    // software-pipelined: prefetch row r+1 before processing row r
    const float4* lp = (const float4*)rowptr;
    float4 c0 = lp[0], c1 = lp[1], c2 = lp[2], c3 = lp[3];

    #pragma unroll
    for (int r = 0; r < ROWS_PER_WAVE; ++r) {
        float4 n0, n1, n2, n3;
        if (r + 1 < ROWS_PER_WAVE) {
            const float4* np = (const float4*)(rowptr + (size_t)(r + 1) * WDIM);
            n0 = np[0]; n1 = np[1]; n2 = np[2]; n3 = np[3];
        }

        float p[16];
        p[0]  = c0.x;         p[1]  = p[0]  + c0.y;
        p[2]  = p[1]  + c0.z; p[3]  = p[2]  + c0.w;
        p[4]  = p[3]  + c1.x; p[5]  = p[4]  + c1.y;
        p[6]  = p[5]  + c1.z; p[7]  = p[6]  + c1.w;
        p[8]  = p[7]  + c2.x; p[9]  = p[8]  + c2.y;
        p[10] = p[9]  + c2.z; p[11] = p[10] + c2.w;
        p[12] = p[11] + c3.x; p[13] = p[12] + c3.y;
        p[14] = p[13] + c3.z; p[15] = p[14] + c3.w;

        // one wave-inclusive scan of lane totals
        float T = p[15];
        float wscan = T;
        #pragma unroll
        for (int off = 1; off < 64; off <<= 1) {
            float u = __shfl_up(wscan, off, 64);
            if (lane >= off) wscan += u;
        }
        float E = wscan - T;   // exclusive base for this lane's chunk

        // 8x ds_write_b64, stride-18 layout (conflict-free)
        float2* Pw = (float2*)(P + 18 * lane);
        #pragma unroll
        for (int j = 0; j < 8; ++j)
            Pw[j] = make_float2(E + p[2 * j], E + p[2 * j + 1]);

        __builtin_amdgcn_wave_barrier();   // write->read order; DS pipe in-order per wave

        const int row = hrow0 + r;         // batch-local row
        if (va && (y1a <= row) && (row < y2a)) acca += P[ra] - P[la];
        if (vb && (y1b <= row) && (row < y2b)) accb += P[rb] - P[lb];

        __builtin_amdgcn_wave_barrier();   // next row's writes after these reads

        c0 = n0; c1 = n1; c2 = n2; c3 = n3;
    }

    if (va && acca != 0.0f) atomicAdd(&ws_box[b * NBOX + lane], acca);
    if (vb && accb != 0.0f) atomicAdd(&ws_box[b * NBOX + 64 + lane], accb);
}

// ---------------------------------------------------------------------------
// Kernel 2: loss = sum over boxes of relu(1 - (valid ? box_sum : 0)).
// ---------------------------------------------------------------------------
__global__ void finalize_kernel(const float* __restrict__ ws_box,
                                const int* __restrict__ bboxes,
                                float* __restrict__ out) {
    __shared__ float red[THREADS / 64];
    const int t = threadIdx.x;
    float local = 0.0f;
    for (int idx = t; idx < BATCH * NBOX; idx += THREADS) {
        const int4 q = ((const int4*)bboxes)[idx];
        int x1 = min(max(q.x, 0), WDIM), y1 = min(max(q.y, 0), WDIM);
        int x2 = min(max(q.z, 0), WDIM), y2 = min(max(q.w, 0), WDIM);
        bool valid = (x2 > x1) && (y2 > y1);
        float s = valid ? ws_box[idx] : 0.0f;
        local += fmaxf(1.0f - s, 0.0f);
    }
    #pragma unroll
    for (int off = 32; off > 0; off >>= 1)
        local += __shfl_down(local, off, 64);
    if ((t & 63) == 0) red[t >> 6] = local;
    __syncthreads();
    if (t == 0) {
        float r = 0.0f;
        #pragma unroll
        for (int w = 0; w < THREADS / 64; ++w) r += red[w];
        out[0] = r;
    }
}

// ---------------------------------------------------------------------------
extern "C" void kernel_launch(void* const* d_in, const int* in_sizes, int n_in,
                              void* d_out, int out_size, void* d_ws, size_t ws_size,
                              hipStream_t stream) {
    const float* img    = (const float*)d_in[0];   // (32,1,1024,1024) fp32
    const int*   bboxes = (const int*)d_in[1];     // (32,96,4) int32
    float* out = (float*)d_out;
    float* ws_box = (float*)d_ws;

    zero_ws_kernel<<<(BATCH * NBOX + THREADS - 1) / THREADS, THREADS, 0, stream>>>(ws_box);
    box_accum_kernel<<<NBLOCKS, THREADS, 0, stream>>>(img, bboxes, ws_box);
    finalize_kernel<<<1, THREADS, 0, stream>>>(ws_box, bboxes, out);
}